// Round 8
// baseline (491.422 us; speedup 1.0000x reference)
//
#include <hip/hip_runtime.h>
#include <float.h>

#define L_TOK 65536
#define DIM   64
#define NCODE 1024

// ---------------------------------------------------------------------------
// Kernel A: per-code ||e||^2 (fp32), sequential-k chain.
// ---------------------------------------------------------------------------
__global__ __launch_bounds__(256) void esum_kernel(const float* __restrict__ emb,
                                                   float* __restrict__ esum) {
    int n = blockIdx.x * 256 + threadIdx.x;
    if (n >= NCODE) return;
    const float* e = emb + ((size_t)n << 6);
    float s = 0.f;
#pragma unroll
    for (int k = 0; k < DIM; ++k) s = fmaf(e[k], e[k], s);
    esum[n] = s;
}

// ---------------------------------------------------------------------------
// Kernel B: argmin.
// Evidence history:
//   r2/3/5/6: z pinned to "registers" lands in AGPRs (VGPR=44), 2 VALU/FMA.
//   r4: LDS z, loop-invariant reads -> LICM -> scratch (2.4 GB HBM).
//   r7: LDS z + anti-LICM opaque SGPR works (no scratch, VGPR=32) BUT
//       (a) 9.0M LDS bank-conflict cycles ((tok&7)<<4 swizzle too narrow),
//       (b) e-rows via s_load share lgkmcnt with ds_read; LDS/SMEM complete
//           out of order -> compiler must drain lgkmcnt(0) per use -> inner
//           loop serialized, per-SIMD VALU duty ~35% (172us vs 59us issue).
// This round:
//   (1) swizzle widened to (tok&15)<<4: 16 distinct 16B slots per 16-lane
//       b128 phase = 2 lanes/bank = conflict-free (m136).
//   (2) e-rows loaded via VMEM: wave-uniform address made opaque-divergent
//       (VGPR-zero asm) so they CANNOT scalarize to s_load. Hot loop then
//       splits counters: vmcnt (e, counted pipelined waits) vs lgkmcnt
//       (ds_read only, in-order fine waits). Embedding is L2-resident;
//       uniform-address loads coalesce to one request/wave-op.
// Numerics bitwise-identical: sequential k=0..63 fmaf chains (float4
// x,y,z,w, ascending chunks), d = fmaf(a,-2,zs+esum) == (zs+esum)-2a,
// ascending strict '<' scan, lowest-index tie-break across waves.
// ---------------------------------------------------------------------------
__global__ __launch_bounds__(512, 8) void argmin_kernel(const float* __restrict__ z,
                                                        const float* __restrict__ emb,
                                                        const float* __restrict__ esum,
                                                        float* __restrict__ idx_out) {
    __shared__ float zl[64 * 64];   // swizzled row-major [tok][k], 16 KB
    __shared__ float sb[8][64];
    __shared__ int   si[8][64];

    const int t    = threadIdx.x;
    const int lane = t & 63;
    const int wid  = __builtin_amdgcn_readfirstlane(t >> 6);
    char* zbytes   = (char*)zl;

    // Stage z tile: coalesced global read, swizzled b128 LDS writes.
    {
        const int tok = t >> 3;          // 0..63
        const int kk  = (t & 7) * 8;     // 0,8,..,56
        const int swt = (tok & 15) << 4;
        const float* src = z + ((size_t)(blockIdx.x * 64 + tok) << 6) + kk;
        float4 v0 = ((const float4*)src)[0];
        float4 v1 = ((const float4*)src)[1];
        *(float4*)(zbytes + tok * 256 + ((kk * 4) ^ swt))      = v0;
        *(float4*)(zbytes + tok * 256 + ((kk * 4 + 16) ^ swt)) = v1;
    }
    __syncthreads();

    const int rowbase = lane * 256;
    const int sw      = (lane & 15) << 4;

    // ||z||^2, sequential k (chunk-ascending, x,y,z,w order).
    float zs = 0.f;
#pragma unroll
    for (int k0 = 0; k0 < 64; k0 += 4) {
        float4 zk = *(const float4*)(zbytes + rowbase + ((k0 * 4) ^ sw));
        zs = fmaf(zk.x, zk.x, zs);
        zs = fmaf(zk.y, zk.y, zs);
        zs = fmaf(zk.z, zk.z, zs);
        zs = fmaf(zk.w, zk.w, zs);
    }

    // Opaque per-lane zero: forces the e addresses to be treated as divergent
    // -> VMEM global_load (vmcnt), not scalarized s_load (lgkmcnt).
    int vzero = 0;
    asm volatile("" : "+v"(vzero));
    const float* embv = emb + vzero;

    float best = FLT_MAX;
    int   bi   = 0;
    const int cbase = wid * 128;     // wave-uniform

    for (int c0 = cbase; c0 < cbase + 128; c0 += 8) {
        int szero = 0;
        asm volatile("" : "+s"(szero));  // opaque per-iter def: blocks LICM/PRE
        const int rb = rowbase + szero;  // of the LDS reads below

        const float* __restrict__ e0 = embv + ((size_t)(c0 + 0) << 6);
        const float* __restrict__ e1 = embv + ((size_t)(c0 + 1) << 6);
        const float* __restrict__ e2 = embv + ((size_t)(c0 + 2) << 6);
        const float* __restrict__ e3 = embv + ((size_t)(c0 + 3) << 6);
        const float* __restrict__ e4 = embv + ((size_t)(c0 + 4) << 6);
        const float* __restrict__ e5 = embv + ((size_t)(c0 + 5) << 6);
        const float* __restrict__ e6 = embv + ((size_t)(c0 + 6) << 6);
        const float* __restrict__ e7 = embv + ((size_t)(c0 + 7) << 6);
        float a0 = 0.f, a1 = 0.f, a2 = 0.f, a3 = 0.f;
        float a4 = 0.f, a5 = 0.f, a6 = 0.f, a7 = 0.f;
#pragma unroll
        for (int k0 = 0; k0 < 64; k0 += 4) {
            float4 zk = *(const float4*)(zbytes + rb + ((k0 * 4) ^ sw));
            float4 f0 = *(const float4*)(e0 + k0);
            float4 f1 = *(const float4*)(e1 + k0);
            float4 f2 = *(const float4*)(e2 + k0);
            float4 f3 = *(const float4*)(e3 + k0);
            float4 f4 = *(const float4*)(e4 + k0);
            float4 f5 = *(const float4*)(e5 + k0);
            float4 f6 = *(const float4*)(e6 + k0);
            float4 f7 = *(const float4*)(e7 + k0);
            a0 = fmaf(zk.x, f0.x, a0); a0 = fmaf(zk.y, f0.y, a0);
            a0 = fmaf(zk.z, f0.z, a0); a0 = fmaf(zk.w, f0.w, a0);
            a1 = fmaf(zk.x, f1.x, a1); a1 = fmaf(zk.y, f1.y, a1);
            a1 = fmaf(zk.z, f1.z, a1); a1 = fmaf(zk.w, f1.w, a1);
            a2 = fmaf(zk.x, f2.x, a2); a2 = fmaf(zk.y, f2.y, a2);
            a2 = fmaf(zk.z, f2.z, a2); a2 = fmaf(zk.w, f2.w, a2);
            a3 = fmaf(zk.x, f3.x, a3); a3 = fmaf(zk.y, f3.y, a3);
            a3 = fmaf(zk.z, f3.z, a3); a3 = fmaf(zk.w, f3.w, a3);
            a4 = fmaf(zk.x, f4.x, a4); a4 = fmaf(zk.y, f4.y, a4);
            a4 = fmaf(zk.z, f4.z, a4); a4 = fmaf(zk.w, f4.w, a4);
            a5 = fmaf(zk.x, f5.x, a5); a5 = fmaf(zk.y, f5.y, a5);
            a5 = fmaf(zk.z, f5.z, a5); a5 = fmaf(zk.w, f5.w, a5);
            a6 = fmaf(zk.x, f6.x, a6); a6 = fmaf(zk.y, f6.y, a6);
            a6 = fmaf(zk.z, f6.z, a6); a6 = fmaf(zk.w, f6.w, a6);
            a7 = fmaf(zk.x, f7.x, a7); a7 = fmaf(zk.y, f7.y, a7);
            a7 = fmaf(zk.z, f7.z, a7); a7 = fmaf(zk.w, f7.w, a7);
        }
        float d0 = fmaf(a0, -2.0f, zs + esum[c0 + 0]);
        float d1 = fmaf(a1, -2.0f, zs + esum[c0 + 1]);
        float d2 = fmaf(a2, -2.0f, zs + esum[c0 + 2]);
        float d3 = fmaf(a3, -2.0f, zs + esum[c0 + 3]);
        float d4 = fmaf(a4, -2.0f, zs + esum[c0 + 4]);
        float d5 = fmaf(a5, -2.0f, zs + esum[c0 + 5]);
        float d6 = fmaf(a6, -2.0f, zs + esum[c0 + 6]);
        float d7 = fmaf(a7, -2.0f, zs + esum[c0 + 7]);
        if (d0 < best) { best = d0; bi = c0 + 0; }
        if (d1 < best) { best = d1; bi = c0 + 1; }
        if (d2 < best) { best = d2; bi = c0 + 2; }
        if (d3 < best) { best = d3; bi = c0 + 3; }
        if (d4 < best) { best = d4; bi = c0 + 4; }
        if (d5 < best) { best = d5; bi = c0 + 5; }
        if (d6 < best) { best = d6; bi = c0 + 6; }
        if (d7 < best) { best = d7; bi = c0 + 7; }
    }

    sb[wid][lane] = best;
    si[wid][lane] = bi;
    __syncthreads();

    if (t < 64) {
        float b = sb[0][lane];
        int   i = si[0][lane];
#pragma unroll
        for (int w = 1; w < 8; ++w) {
            float ob = sb[w][lane];
            int   oi = si[w][lane];
            if (ob < b || (ob == b && oi < i)) { b = ob; i = oi; }
        }
        idx_out[blockIdx.x * 64 + lane] = (float)i;
    }
}

// ---------------------------------------------------------------------------
// Kernel C: z_q_st + per-block f64 loss partials (unchanged).
// ---------------------------------------------------------------------------
__global__ __launch_bounds__(256) void output_kernel(const float* __restrict__ z,
                                                     const float* __restrict__ emb,
                                                     const float* __restrict__ idx_f,
                                                     float* __restrict__ zq_out,
                                                     double* __restrict__ partials) {
    int gid = blockIdx.x * 256 + threadIdx.x;
    int l = gid >> 6;
    int k = gid & 63;
    int idx = (int)idx_f[l];

    float zv = z[gid];
    float ev = emb[(idx << 6) + k];
    float t    = ev - zv;
    float outv = zv + t;
    zq_out[gid] = outv;

    float sq = t * t;

    __shared__ double red[256];
    red[threadIdx.x] = (double)sq;
    __syncthreads();
    for (int s = 128; s > 0; s >>= 1) {
        if (threadIdx.x < s) red[threadIdx.x] += red[threadIdx.x + s];
        __syncthreads();
    }
    if (threadIdx.x == 0) partials[blockIdx.x] = red[0];
}

// ---------------------------------------------------------------------------
// Kernel D: final deterministic reduction (unchanged).
// ---------------------------------------------------------------------------
__global__ __launch_bounds__(256) void loss_kernel(const double* __restrict__ partials,
                                                   float* __restrict__ loss_out) {
    __shared__ double red[256];
    int t = threadIdx.x;
    double s = 0.0;
    for (int i = 0; i < 64; ++i) s += partials[t * 64 + i];
    red[t] = s;
    __syncthreads();
    for (int st = 128; st > 0; st >>= 1) {
        if (t < st) red[t] += red[t + st];
        __syncthreads();
    }
    if (t == 0) {
        double m  = red[0] / (double)(L_TOK * DIM);
        float  mf = (float)m;
        loss_out[0] = 0.25f * mf + mf;
    }
}

extern "C" void kernel_launch(void* const* d_in, const int* in_sizes, int n_in,
                              void* d_out, int out_size, void* d_ws, size_t ws_size,
                              hipStream_t stream) {
    const float* z   = (const float*)d_in[0];
    const float* emb = (const float*)d_in[1];

    float* out   = (float*)d_out;
    float* zq    = out;                 // [0, 4194304)
    float* loss  = out + 4194304;       // [4194304]
    float* idxf  = out + 4194305;       // [4194305, 4259841)

    float*  esum     = (float*)d_ws;                          // 1024 f32
    double* partials = (double*)((char*)d_ws + 8192);         // 16384 f64

    esum_kernel  <<<4,     256, 0, stream>>>(emb, esum);
    argmin_kernel<<<1024,  512, 0, stream>>>(z, emb, esum, idxf);
    output_kernel<<<16384, 256, 0, stream>>>(z, emb, idxf, zq, partials);
    loss_kernel  <<<1,     256, 0, stream>>>(partials, loss);
}

// Round 9
// 143.161 us; speedup vs baseline: 3.4327x; 3.4327x over previous
//
#include <hip/hip_runtime.h>
#include <float.h>

#define L_TOK 65536
#define DIM   64
#define NCODE 1024

// ---------------------------------------------------------------------------
// Kernel A: per-code ||e||^2 (fp32), sequential-k chain.
// ---------------------------------------------------------------------------
__global__ __launch_bounds__(256) void esum_kernel(const float* __restrict__ emb,
                                                   float* __restrict__ esum) {
    int n = blockIdx.x * 256 + threadIdx.x;
    if (n >= NCODE) return;
    const float* e = emb + ((size_t)n << 6);
    float s = 0.f;
#pragma unroll
    for (int k = 0; k < DIM; ++k) s = fmaf(e[k], e[k], s);
    esum[n] = s;
}

// ---------------------------------------------------------------------------
// Kernel B: argmin.
// Evidence history:
//   r2/5/6: lane=token, e via s_load: 180us. SMEM-delivery-bound.
//   r4: LDS z, loop-invariant reads -> LICM -> scratch (2.4 GB, 807us).
//   r7: LDS z + anti-LICM + swizzle: 172us. Still SMEM-bound: 16K
//       s_load_dwordx16 per CU through the shared scalar pipe + lgkmcnt
//       drains (ds/smem mixed). Real VALU duty ~35-40% (gfx94x-formula
//       VALUBusy is ~2x overstated). Bank conflicts fixed ((tok&15)<<4).
//   r8: e via per-lane VMEM: 494us. Broadcast data on the vector path +
//       32-VGPR batching = serialized vmcnt waits. Reverted.
// This round: 2 TOKENS PER LANE. z-tile = 128 rows (32 KB LDS, r7 swizzle +
// anti-LICM). Per-wave scalar loads unchanged but serve 2x tokens -> total
// SMEM requests per CU halve (8192); every e-batch feeds 2x fmacs so lgkm
// drain stalls amortize 2x. VALU floor invariant (54.6us/SIMD at 4
// waves/SIMD; launch_bounds(512,4) -> VGPR cap 128, ~55 used, no scratch).
// Numerics bitwise-identical: per-(token,code) sequential k=0..63 fmaf
// chains, d = fmaf(a,-2,zs+esum) == (zs+esum)-2a, ascending strict '<',
// lowest-index tie-break across waves.
// ---------------------------------------------------------------------------
__global__ __launch_bounds__(512, 4) void argmin_kernel(const float* __restrict__ z,
                                                        const float* __restrict__ emb,
                                                        const float* __restrict__ esum,
                                                        float* __restrict__ idx_out) {
    __shared__ float zl[128 * 64];   // swizzled row-major [tok][k], 32 KB
    __shared__ float sb[8][128];
    __shared__ int   si[8][128];

    const int t    = threadIdx.x;
    const int lane = t & 63;
    const int wid  = __builtin_amdgcn_readfirstlane(t >> 6);
    char* zbytes   = (char*)zl;

    // Stage z tile: 128 rows; each thread stages 16 consecutive floats of one
    // row (4 float4s), coalesced global read, swizzled LDS writes.
    {
        const int tok = t >> 2;            // 0..127
        const int kk  = (t & 3) * 16;      // 0,16,32,48
        const int swt = (tok & 15) << 4;
        const float* src = z + ((size_t)(blockIdx.x * 128 + tok) << 6) + kk;
        float4 v0 = ((const float4*)src)[0];
        float4 v1 = ((const float4*)src)[1];
        float4 v2 = ((const float4*)src)[2];
        float4 v3 = ((const float4*)src)[3];
        *(float4*)(zbytes + tok * 256 + (((kk +  0) * 4) ^ swt)) = v0;
        *(float4*)(zbytes + tok * 256 + (((kk +  4) * 4) ^ swt)) = v1;
        *(float4*)(zbytes + tok * 256 + (((kk +  8) * 4) ^ swt)) = v2;
        *(float4*)(zbytes + tok * 256 + (((kk + 12) * 4) ^ swt)) = v3;
    }
    __syncthreads();

    const int rbA = lane * 256;            // token A = lane
    const int rbB = rbA + 64 * 256;        // token B = lane + 64
    const int sw  = (lane & 15) << 4;      // same for A and B ((lane+64)&15)

    // ||z||^2 per token, sequential k (chunk-ascending, x,y,z,w order).
    float zsA = 0.f, zsB = 0.f;
#pragma unroll
    for (int k0 = 0; k0 < 64; k0 += 4) {
        float4 a = *(const float4*)(zbytes + rbA + ((k0 * 4) ^ sw));
        float4 b = *(const float4*)(zbytes + rbB + ((k0 * 4) ^ sw));
        zsA = fmaf(a.x, a.x, zsA); zsA = fmaf(a.y, a.y, zsA);
        zsA = fmaf(a.z, a.z, zsA); zsA = fmaf(a.w, a.w, zsA);
        zsB = fmaf(b.x, b.x, zsB); zsB = fmaf(b.y, b.y, zsB);
        zsB = fmaf(b.z, b.z, zsB); zsB = fmaf(b.w, b.w, zsB);
    }

    float bestA = FLT_MAX, bestB = FLT_MAX;
    int   biA   = 0,       biB   = 0;
    const int cbase = wid * 128;           // wave-uniform

    for (int c0 = cbase; c0 < cbase + 128; c0 += 8) {
        int szero = 0;
        asm volatile("" : "+s"(szero));    // opaque per-iter def: blocks LICM
        const int rA = rbA + szero;
        const int rB = rbB + szero;

        const float* __restrict__ e0 = emb + ((size_t)(c0 + 0) << 6);
        const float* __restrict__ e1 = emb + ((size_t)(c0 + 1) << 6);
        const float* __restrict__ e2 = emb + ((size_t)(c0 + 2) << 6);
        const float* __restrict__ e3 = emb + ((size_t)(c0 + 3) << 6);
        const float* __restrict__ e4 = emb + ((size_t)(c0 + 4) << 6);
        const float* __restrict__ e5 = emb + ((size_t)(c0 + 5) << 6);
        const float* __restrict__ e6 = emb + ((size_t)(c0 + 6) << 6);
        const float* __restrict__ e7 = emb + ((size_t)(c0 + 7) << 6);
        float a0 = 0.f, a1 = 0.f, a2 = 0.f, a3 = 0.f;
        float a4 = 0.f, a5 = 0.f, a6 = 0.f, a7 = 0.f;
        float b0 = 0.f, b1 = 0.f, b2 = 0.f, b3 = 0.f;
        float b4 = 0.f, b5 = 0.f, b6 = 0.f, b7 = 0.f;
#pragma unroll
        for (int k0 = 0; k0 < 64; k0 += 4) {
            float4 za = *(const float4*)(zbytes + rA + ((k0 * 4) ^ sw));
            float4 zb = *(const float4*)(zbytes + rB + ((k0 * 4) ^ sw));
            float4 f0 = *(const float4*)(e0 + k0);
            float4 f1 = *(const float4*)(e1 + k0);
            float4 f2 = *(const float4*)(e2 + k0);
            float4 f3 = *(const float4*)(e3 + k0);
            float4 f4 = *(const float4*)(e4 + k0);
            float4 f5 = *(const float4*)(e5 + k0);
            float4 f6 = *(const float4*)(e6 + k0);
            float4 f7 = *(const float4*)(e7 + k0);
            a0 = fmaf(za.x, f0.x, a0); a0 = fmaf(za.y, f0.y, a0);
            a0 = fmaf(za.z, f0.z, a0); a0 = fmaf(za.w, f0.w, a0);
            a1 = fmaf(za.x, f1.x, a1); a1 = fmaf(za.y, f1.y, a1);
            a1 = fmaf(za.z, f1.z, a1); a1 = fmaf(za.w, f1.w, a1);
            a2 = fmaf(za.x, f2.x, a2); a2 = fmaf(za.y, f2.y, a2);
            a2 = fmaf(za.z, f2.z, a2); a2 = fmaf(za.w, f2.w, a2);
            a3 = fmaf(za.x, f3.x, a3); a3 = fmaf(za.y, f3.y, a3);
            a3 = fmaf(za.z, f3.z, a3); a3 = fmaf(za.w, f3.w, a3);
            a4 = fmaf(za.x, f4.x, a4); a4 = fmaf(za.y, f4.y, a4);
            a4 = fmaf(za.z, f4.z, a4); a4 = fmaf(za.w, f4.w, a4);
            a5 = fmaf(za.x, f5.x, a5); a5 = fmaf(za.y, f5.y, a5);
            a5 = fmaf(za.z, f5.z, a5); a5 = fmaf(za.w, f5.w, a5);
            a6 = fmaf(za.x, f6.x, a6); a6 = fmaf(za.y, f6.y, a6);
            a6 = fmaf(za.z, f6.z, a6); a6 = fmaf(za.w, f6.w, a6);
            a7 = fmaf(za.x, f7.x, a7); a7 = fmaf(za.y, f7.y, a7);
            a7 = fmaf(za.z, f7.z, a7); a7 = fmaf(za.w, f7.w, a7);
            b0 = fmaf(zb.x, f0.x, b0); b0 = fmaf(zb.y, f0.y, b0);
            b0 = fmaf(zb.z, f0.z, b0); b0 = fmaf(zb.w, f0.w, b0);
            b1 = fmaf(zb.x, f1.x, b1); b1 = fmaf(zb.y, f1.y, b1);
            b1 = fmaf(zb.z, f1.z, b1); b1 = fmaf(zb.w, f1.w, b1);
            b2 = fmaf(zb.x, f2.x, b2); b2 = fmaf(zb.y, f2.y, b2);
            b2 = fmaf(zb.z, f2.z, b2); b2 = fmaf(zb.w, f2.w, b2);
            b3 = fmaf(zb.x, f3.x, b3); b3 = fmaf(zb.y, f3.y, b3);
            b3 = fmaf(zb.z, f3.z, b3); b3 = fmaf(zb.w, f3.w, b3);
            b4 = fmaf(zb.x, f4.x, b4); b4 = fmaf(zb.y, f4.y, b4);
            b4 = fmaf(zb.z, f4.z, b4); b4 = fmaf(zb.w, f4.w, b4);
            b5 = fmaf(zb.x, f5.x, b5); b5 = fmaf(zb.y, f5.y, b5);
            b5 = fmaf(zb.z, f5.z, b5); b5 = fmaf(zb.w, f5.w, b5);
            b6 = fmaf(zb.x, f6.x, b6); b6 = fmaf(zb.y, f6.y, b6);
            b6 = fmaf(zb.z, f6.z, b6); b6 = fmaf(zb.w, f6.w, b6);
            b7 = fmaf(zb.x, f7.x, b7); b7 = fmaf(zb.y, f7.y, b7);
            b7 = fmaf(zb.z, f7.z, b7); b7 = fmaf(zb.w, f7.w, b7);
        }
#pragma unroll
        for (int j = 0; j < 8; ++j) {
            float aj = (j==0?a0:j==1?a1:j==2?a2:j==3?a3:j==4?a4:j==5?a5:j==6?a6:a7);
            float bj = (j==0?b0:j==1?b1:j==2?b2:j==3?b3:j==4?b4:j==5?b5:j==6?b6:b7);
            float es = esum[c0 + j];
            float dA = fmaf(aj, -2.0f, zsA + es);
            float dB = fmaf(bj, -2.0f, zsB + es);
            if (dA < bestA) { bestA = dA; biA = c0 + j; }
            if (dB < bestB) { bestB = dB; biB = c0 + j; }
        }
    }

    sb[wid][lane]      = bestA;
    si[wid][lane]      = biA;
    sb[wid][lane + 64] = bestB;
    si[wid][lane + 64] = biB;
    __syncthreads();

    if (t < 128) {
        float b = sb[0][t];
        int   i = si[0][t];
#pragma unroll
        for (int w = 1; w < 8; ++w) {
            float ob = sb[w][t];
            int   oi = si[w][t];
            if (ob < b || (ob == b && oi < i)) { b = ob; i = oi; }
        }
        idx_out[blockIdx.x * 128 + t] = (float)i;
    }
}

// ---------------------------------------------------------------------------
// Kernel C: z_q_st + per-block f64 loss partials (unchanged).
// ---------------------------------------------------------------------------
__global__ __launch_bounds__(256) void output_kernel(const float* __restrict__ z,
                                                     const float* __restrict__ emb,
                                                     const float* __restrict__ idx_f,
                                                     float* __restrict__ zq_out,
                                                     double* __restrict__ partials) {
    int gid = blockIdx.x * 256 + threadIdx.x;
    int l = gid >> 6;
    int k = gid & 63;
    int idx = (int)idx_f[l];

    float zv = z[gid];
    float ev = emb[(idx << 6) + k];
    float t    = ev - zv;
    float outv = zv + t;
    zq_out[gid] = outv;

    float sq = t * t;

    __shared__ double red[256];
    red[threadIdx.x] = (double)sq;
    __syncthreads();
    for (int s = 128; s > 0; s >>= 1) {
        if (threadIdx.x < s) red[threadIdx.x] += red[threadIdx.x + s];
        __syncthreads();
    }
    if (threadIdx.x == 0) partials[blockIdx.x] = red[0];
}

// ---------------------------------------------------------------------------
// Kernel D: final deterministic reduction (unchanged).
// ---------------------------------------------------------------------------
__global__ __launch_bounds__(256) void loss_kernel(const double* __restrict__ partials,
                                                   float* __restrict__ loss_out) {
    __shared__ double red[256];
    int t = threadIdx.x;
    double s = 0.0;
    for (int i = 0; i < 64; ++i) s += partials[t * 64 + i];
    red[t] = s;
    __syncthreads();
    for (int st = 128; st > 0; st >>= 1) {
        if (t < st) red[t] += red[t + st];
        __syncthreads();
    }
    if (t == 0) {
        double m  = red[0] / (double)(L_TOK * DIM);
        float  mf = (float)m;
        loss_out[0] = 0.25f * mf + mf;
    }
}

extern "C" void kernel_launch(void* const* d_in, const int* in_sizes, int n_in,
                              void* d_out, int out_size, void* d_ws, size_t ws_size,
                              hipStream_t stream) {
    const float* z   = (const float*)d_in[0];
    const float* emb = (const float*)d_in[1];

    float* out   = (float*)d_out;
    float* zq    = out;                 // [0, 4194304)
    float* loss  = out + 4194304;       // [4194304]
    float* idxf  = out + 4194305;       // [4194305, 4259841)

    float*  esum     = (float*)d_ws;                          // 1024 f32
    double* partials = (double*)((char*)d_ws + 8192);         // 16384 f64

    esum_kernel  <<<4,     256, 0, stream>>>(emb, esum);
    argmin_kernel<<<512,   512, 0, stream>>>(z, emb, esum, idxf);
    output_kernel<<<16384, 256, 0, stream>>>(z, emb, idxf, zq, partials);
    loss_kernel  <<<1,     256, 0, stream>>>(partials, loss);
}